// Round 1
// baseline (167.787 us; speedup 1.0000x reference)
//
#include <hip/hip_runtime.h>

#define NB 128
#define NF 512
#define NFRAG 64
#define TROWS (NF * NFRAG)   // 32768 rows per batch
#define NUM_CELLS 64

__device__ __forceinline__ unsigned long long lanemask_le(int lane) {
    return (lane == 63) ? ~0ull : ((1ull << (lane + 1)) - 1ull);
}

// 64-element bitonic sort across the wave, ascending by s, payload e.
__device__ __forceinline__ void bitonic_sort64(float& s, float& e, int lane) {
#pragma unroll
    for (int k = 2; k <= 64; k <<= 1) {
#pragma unroll
        for (int j = k >> 1; j > 0; j >>= 1) {
            float s2 = __shfl_xor(s, j, 64);
            float e2 = __shfl_xor(e, j, 64);
            bool up = ((lane & k) == 0);       // ascending block
            bool lower = ((lane & j) == 0);    // this lane holds the lower index of the pair
            float lo = lower ? s : s2;
            float hi = lower ? s2 : s;
            bool sw = up ? (lo > hi) : (lo < hi);   // no swap on ties (both sides agree)
            if (sw) { s = s2; e = e2; }
        }
    }
}

// Inclusive cummax of e across the wave; returns running max per lane.
__device__ __forceinline__ float cummax64(float e, int lane) {
    float run = e;
#pragma unroll
    for (int d = 1; d < 64; d <<= 1) {
        float t = __shfl_up(run, d, 64);
        if (lane >= d) run = fmaxf(run, t);
    }
    return run;
}

__global__ __launch_bounds__(256) void count_kernel(const float2* __restrict__ frags,
                                                    int* __restrict__ counts) {
    int lane = threadIdx.x & 63;
    int wv = threadIdx.x >> 6;
    int frame = blockIdx.x * 4 + wv;          // < NB*NF
    const float2* fp = frags + (size_t)frame * NFRAG;
    float2 v = fp[lane];
    float s = v.x, e = v.y;
    bitonic_sort64(s, e, lane);
    float run = cummax64(e, lane);
    float pc = __shfl_up(run, 1, 64);
    int ng = (lane > 0) && (s > pc);
    unsigned long long bm = __ballot(ng);
    if (lane == 0) counts[frame] = (int)__popcll(bm) + 1;
}

__global__ __launch_bounds__(512) void scan_kernel(int* __restrict__ cnt,
                                                   float* __restrict__ out_tail) {
    __shared__ int tmp[NF];
    int b = blockIdx.x, t = threadIdx.x;
    int v = cnt[b * NF + t];
    tmp[t] = v;
    __syncthreads();
    for (int d = 1; d < NF; d <<= 1) {
        int x = (t >= d) ? tmp[t - d] : 0;
        __syncthreads();
        tmp[t] += x;
        __syncthreads();
    }
    cnt[b * NF + t] = tmp[t] - v;             // exclusive offsets, in place
    if (t == NF - 1) out_tail[b] = (float)tmp[NF - 1];   // num_groups per batch
}

__global__ __launch_bounds__(256) void resolve_kernel(const float2* __restrict__ frags,
                                                      const float* __restrict__ offsets,
                                                      const int* __restrict__ offs,
                                                      float* __restrict__ out) {
    __shared__ float ssum[4][64];
    __shared__ float esum[4][64];
    __shared__ float csum[4][64];
    __shared__ int   gmx[4][64];
    int lane = threadIdx.x & 63;
    int wv = threadIdx.x >> 6;
    int frame = blockIdx.x * 4 + wv;
    int b = frame >> 9;                        // frame / NF
    const float2* fp = frags + (size_t)frame * NFRAG;
    float2 v = fp[lane];
    float s = v.x, e = v.y;
    bitonic_sort64(s, e, lane);

    float off = offsets[frame];
    const float coef = (float)(64.0 / 44100.0);   // same double->f32 constant as reference
    int sc = (int)floorf((s - off) * coef); if (sc < 0) sc = 0;
    int ec = (int)floorf((e - off) * coef); if (ec > NUM_CELLS - 1) ec = NUM_CELLS - 1;
    int rank = (sc != 0 && ec != NUM_CELLS - 1) ? 1 : 0;

    float run = cummax64(e, lane);
    float pc = __shfl_up(run, 1, 64);
    int ng = (lane > 0) && (s > pc);
    unsigned long long bm = __ballot(ng);
    int gid = (int)__popcll(bm & lanemask_le(lane));   // inclusive popcount = group id
    int G = (int)__popcll(bm) + 1;

    ssum[wv][lane] = 0.f; esum[wv][lane] = 0.f; csum[wv][lane] = 0.f; gmx[wv][lane] = 0;
    __syncthreads();
    if (rank) gmx[wv][gid] = 1;                // benign same-value race
    __syncthreads();
    int ismax = (rank == gmx[wv][gid]);
    if (ismax) {
        atomicAdd(&ssum[wv][gid], s);
        atomicAdd(&esum[wv][gid], e);
        atomicAdd(&csum[wv][gid], 1.0f);
    }
    __syncthreads();
    if (lane < G) {
        int row = offs[frame] + lane;          // batch-global row for group `lane`
        float c = csum[wv][lane];              // >= 1 always
        float2 r = make_float2(ssum[wv][lane] / c, esum[wv][lane] / c);
        ((float2*)out)[(size_t)b * TROWS + row] = r;
    }
}

extern "C" void kernel_launch(void* const* d_in, const int* in_sizes, int n_in,
                              void* d_out, int out_size, void* d_ws, size_t ws_size,
                              hipStream_t stream) {
    const float2* frags = (const float2*)d_in[0];   // [B,F,N,2] float32
    const float* offsets = (const float*)d_in[1];   // [B,F] float32
    float* out = (float*)d_out;
    int* counts = (int*)d_ws;                       // NB*NF ints = 256 KB

    // zero entire output (resolved padding rows must be 0)
    hipMemsetAsync(d_out, 0, (size_t)out_size * sizeof(float), stream);

    count_kernel<<<NB * NF / 4, 256, 0, stream>>>(frags, counts);
    scan_kernel<<<NB, NF, 0, stream>>>(counts, out + (size_t)NB * TROWS * 2);
    resolve_kernel<<<NB * NF / 4, 256, 0, stream>>>(frags, offsets, counts, out);
}

// Round 3
// 59.359 us; speedup vs baseline: 2.8267x; 2.8267x over previous
//
#include <hip/hip_runtime.h>

#define NB 128
#define NF 512
#define NFRAG 64
#define NFRAMES (NB * NF)
#define TROWS (NF * NFRAG)

typedef unsigned long long u64;

// ---------- cross-lane primitives ----------

template<int CTRL, int ROWM, bool BC>
__device__ __forceinline__ float dppf(float x, float old) {
    return __int_as_float(__builtin_amdgcn_update_dpp(
        __float_as_int(old), __float_as_int(x), CTRL, ROWM, 0xF, BC));
}

template<int OFS>
__device__ __forceinline__ float swzf(float x) {
    return __int_as_float(__builtin_amdgcn_ds_swizzle(__float_as_int(x), OFS));
}

// ---------- 64-lane bitonic sort by s (payload e), ascending ----------

#define CMPX(K, J, S2, E2) { \
    bool dsc = ((lane & (K)) != 0) != ((lane & (J)) != 0); \
    bool sw = dsc ? (s < (S2)) : (s > (S2)); \
    s = sw ? (S2) : s; e = sw ? (E2) : e; }

// DPP ctrls: xor1 = quad_perm[1,0,3,2] = 0xB1 ; xor2 = quad_perm[2,3,0,1] = 0x4E
// xor8 = row_ror:8 = 0x128. ds_swizzle BitMode: xor4 = 0x101F, xor16 = 0x401F
// (both match the butterfly table in cdna4_isa.md). xor32 via __shfl_xor (proven R1).
#define ST_DPP(K, J, CTRL) { float s2 = dppf<CTRL, 0xF, true>(s, s); \
    float e2 = dppf<CTRL, 0xF, true>(e, e); CMPX(K, J, s2, e2) }
#define ST_SWZ(K, J, OFS) { float s2 = swzf<OFS>(s); \
    float e2 = swzf<OFS>(e); CMPX(K, J, s2, e2) }
#define ST_SHF(K, J) { float s2 = __shfl_xor(s, J, 64); \
    float e2 = __shfl_xor(e, J, 64); CMPX(K, J, s2, e2) }

__device__ __forceinline__ void sort64(float& s, float& e, int lane) {
    ST_DPP(2, 1, 0xB1)
    ST_DPP(4, 2, 0x4E)  ST_DPP(4, 1, 0xB1)
    ST_SWZ(8, 4, 0x101F) ST_DPP(8, 2, 0x4E) ST_DPP(8, 1, 0xB1)
    ST_DPP(16, 8, 0x128) ST_SWZ(16, 4, 0x101F) ST_DPP(16, 2, 0x4E) ST_DPP(16, 1, 0xB1)
    ST_SWZ(32, 16, 0x401F) ST_DPP(32, 8, 0x128) ST_SWZ(32, 4, 0x101F) ST_DPP(32, 2, 0x4E) ST_DPP(32, 1, 0xB1)
    ST_SHF(64, 32)
    ST_SWZ(64, 16, 0x401F) ST_DPP(64, 8, 0x128) ST_SWZ(64, 4, 0x101F) ST_DPP(64, 2, 0x4E) ST_DPP(64, 1, 0xB1)
}

// ---------- wave64 inclusive scans via DPP (canonical GCN row_shr/row_bcast idiom) ----------

__device__ __forceinline__ float scan_max(float x) {
    const float NI = __int_as_float(0xFF800000u);  // -inf identity
    x = fmaxf(x, dppf<0x111, 0xF, false>(x, NI));  // row_shr:1
    x = fmaxf(x, dppf<0x112, 0xF, false>(x, NI));  // row_shr:2
    x = fmaxf(x, dppf<0x114, 0xF, false>(x, NI));  // row_shr:4
    x = fmaxf(x, dppf<0x118, 0xF, false>(x, NI));  // row_shr:8
    x = fmaxf(x, dppf<0x142, 0xA, false>(x, NI));  // row_bcast15 -> rows 1,3
    x = fmaxf(x, dppf<0x143, 0xC, false>(x, NI));  // row_bcast31 -> rows 2,3
    return x;
}

__device__ __forceinline__ float scan_sum(float x) {
    x += dppf<0x111, 0xF, false>(x, 0.0f);
    x += dppf<0x112, 0xF, false>(x, 0.0f);
    x += dppf<0x114, 0xF, false>(x, 0.0f);
    x += dppf<0x118, 0xF, false>(x, 0.0f);
    x += dppf<0x142, 0xA, false>(x, 0.0f);
    x += dppf<0x143, 0xC, false>(x, 0.0f);
    return x;
}

// ---------- main per-frame kernel ----------
// MODE 0: packed rows to scratch + counts; MODE 1: direct write at scanned offsets;
// MODE 2: counts only.
template<int MODE>
__global__ __launch_bounds__(256) void frag_kernel(const float2* __restrict__ frags,
                                                   const float* __restrict__ offsets,
                                                   int* __restrict__ counts,
                                                   const int* __restrict__ offs,
                                                   float2* __restrict__ rows,
                                                   float* __restrict__ out) {
    int lane = threadIdx.x & 63;
    int frame = blockIdx.x * 4 + (threadIdx.x >> 6);
    float2 v = frags[(size_t)frame * NFRAG + lane];
    float s = v.x, e = v.y;
    sort64(s, e, lane);

    // group starts: s_i > cummax(e)_{i-1}
    float run = scan_max(e);
    float prev = __shfl_up(run, 1, 64);
    bool ng = (lane > 0) && (s > prev);
    u64 gs = __ballot(ng) | 1ull;

    if (MODE == 2) {
        if (lane == 0) counts[frame] = (int)__popcll(gs);
        return;
    }

    // grid cells & rank (identical FP ops to reference)
    float off = offsets[frame];
    const float coef = (float)(64.0 / 44100.0);
    int sc = (int)floorf((s - off) * coef); if (sc < 0) sc = 0;
    int ec = (int)floorf((e - off) * coef); if (ec > 63) ec = 63;
    int rank = (sc != 0 && ec != 63) ? 1 : 0;
    u64 r1 = __ballot(rank == 1);

    // my group's span [start, end] from the wave-uniform gs mask
    u64 le_bit = 1ull << lane;
    u64 le_mask = (le_bit << 1) - 1ull;              // bits <= lane (lane63-safe)
    int start = 63 - __builtin_clzll(gs & le_mask);  // nonzero: bit0 always set
    u64 above = gs & ~le_mask;
    int end = above ? (__builtin_ctzll(above) - 1) : 63;
    u64 span = (((1ull << end) << 1) - 1ull) & ~((1ull << start) - 1ull);

    int gmax = ((r1 & span) != 0ull) ? 1 : 0;
    bool ismax = (rank == gmax);
    u64 im = __ballot(ismax);
    float cnt = (float)__popcll(im & span);          // >= 1 always

    // per-group sums via prefix-sum differencing
    float ps = scan_sum(ismax ? s : 0.0f);
    float pe = scan_sum(ismax ? e : 0.0f);
    float bs = __shfl(ps, start - 1, 64);
    float be = __shfl(pe, start - 1, 64);
    if (start == 0) { bs = 0.0f; be = 0.0f; }

    int gid = (int)__popcll(gs & le_mask) - 1;       // starts at-or-below me, minus 1

    if (lane == end) {
        float2 r;
        r.x = (ps - bs) / cnt;
        r.y = (pe - be) / cnt;
        if (MODE == 0) {
            rows[(size_t)frame * NFRAG + gid] = r;
        } else {
            int b = frame >> 9;
            ((float2*)out)[(size_t)b * TROWS + offs[frame] + gid] = r;
        }
    }
    if (MODE == 0 && lane == 0) counts[frame] = (int)__popcll(gs);
}

// ---------- per-batch exclusive scan of frame group counts ----------

__global__ __launch_bounds__(512) void scan_kernel(const int* __restrict__ cnt,
                                                   int* __restrict__ offs,
                                                   float* __restrict__ out_tail) {
    __shared__ int tmp[NF];
    int b = blockIdx.x, t = threadIdx.x;
    int v = cnt[b * NF + t];
    tmp[t] = v;
    __syncthreads();
    for (int d = 1; d < NF; d <<= 1) {
        int x = (t >= d) ? tmp[t - d] : 0;
        __syncthreads();
        tmp[t] += x;
        __syncthreads();
    }
    offs[b * NF + t] = tmp[t] - v;                   // exclusive
    if (t == NF - 1) out_tail[b] = (float)tmp[NF - 1];
}

// ---------- compaction: scratch rows -> final batch-global rows ----------

__global__ __launch_bounds__(256) void compact_kernel(const float2* __restrict__ rows,
                                                      const int* __restrict__ cnt,
                                                      const int* __restrict__ offs,
                                                      float* __restrict__ out) {
    int lane = threadIdx.x & 63;
    int frame = blockIdx.x * 4 + (threadIdx.x >> 6);
    int G = cnt[frame];
    if (lane < G) {
        int b = frame >> 9;
        ((float2*)out)[(size_t)b * TROWS + offs[frame] + lane] =
            rows[(size_t)frame * NFRAG + lane];
    }
}

extern "C" void kernel_launch(void* const* d_in, const int* in_sizes, int n_in,
                              void* d_out, int out_size, void* d_ws, size_t ws_size,
                              hipStream_t stream) {
    const float2* frags = (const float2*)d_in[0];   // [B,F,N,2] f32
    const float* offsets = (const float*)d_in[1];   // [B,F] f32
    float* out = (float*)d_out;

    int* counts = (int*)d_ws;
    int* offs = counts + NFRAMES;
    float2* rows = (float2*)((char*)d_ws + (size_t)2 * NFRAMES * sizeof(int));
    size_t need = (size_t)2 * NFRAMES * sizeof(int) + (size_t)NFRAMES * NFRAG * sizeof(float2);

    hipMemsetAsync(d_out, 0, (size_t)out_size * sizeof(float), stream);
    float* tail = out + (size_t)NB * TROWS * 2;

    if (ws_size >= need) {
        frag_kernel<0><<<NFRAMES / 4, 256, 0, stream>>>(frags, offsets, counts, nullptr, rows, nullptr);
        scan_kernel<<<NB, NF, 0, stream>>>(counts, offs, tail);
        compact_kernel<<<NFRAMES / 4, 256, 0, stream>>>(rows, counts, offs, out);
    } else {
        frag_kernel<2><<<NFRAMES / 4, 256, 0, stream>>>(frags, offsets, counts, nullptr, nullptr, nullptr);
        scan_kernel<<<NB, NF, 0, stream>>>(counts, offs, tail);
        frag_kernel<1><<<NFRAMES / 4, 256, 0, stream>>>(frags, offsets, counts, offs, nullptr, out);
    }
}

// Round 4
// 56.954 us; speedup vs baseline: 2.9460x; 1.0422x over previous
//
#include <hip/hip_runtime.h>

#define NB 128
#define NF 512
#define NFRAG 64
#define NFRAMES (NB * NF)
#define TROWS (NF * NFRAG)

typedef unsigned long long u64;

// ---------- cross-lane primitives (all R3-proven) ----------

template<int CTRL, int ROWM, bool BC>
__device__ __forceinline__ float dppf(float x, float old) {
    return __int_as_float(__builtin_amdgcn_update_dpp(
        __float_as_int(old), __float_as_int(x), CTRL, ROWM, 0xF, BC));
}

template<int OFS>
__device__ __forceinline__ float swzf(float x) {
    return __int_as_float(__builtin_amdgcn_ds_swizzle(__float_as_int(x), OFS));
}

// ---------- 64-lane bitonic sort, 4 frames per wave interleaved (ILP) ----------
// DPP ctrls: xor1 = quad_perm 0xB1 ; xor2 = quad_perm 0x4E ; xor8 = row_ror:8 0x128
// ds_swizzle BitMode: xor4 = 0x101F, xor16 = 0x401F ; xor32 via __shfl_xor.

#define QN 4

#define CMPX_Q(K, J) { \
    bool dsc = ((lane & (K)) != 0) != ((lane & (J)) != 0); \
    _Pragma("unroll") for (int q = 0; q < QN; ++q) { \
        bool sw = dsc ? (s[q] < s2[q]) : (s[q] > s2[q]); \
        s[q] = sw ? s2[q] : s[q]; e[q] = sw ? e2[q] : e[q]; } }

#define ST_DPP_Q(K, J, CTRL) { float s2[QN], e2[QN]; \
    _Pragma("unroll") for (int q = 0; q < QN; ++q) { \
        s2[q] = dppf<CTRL, 0xF, true>(s[q], s[q]); \
        e2[q] = dppf<CTRL, 0xF, true>(e[q], e[q]); } \
    CMPX_Q(K, J) }

#define ST_SWZ_Q(K, J, OFS) { float s2[QN], e2[QN]; \
    _Pragma("unroll") for (int q = 0; q < QN; ++q) { \
        s2[q] = swzf<OFS>(s[q]); e2[q] = swzf<OFS>(e[q]); } \
    CMPX_Q(K, J) }

#define ST_SHF_Q(K, J) { float s2[QN], e2[QN]; \
    _Pragma("unroll") for (int q = 0; q < QN; ++q) { \
        s2[q] = __shfl_xor(s[q], J, 64); e2[q] = __shfl_xor(e[q], J, 64); } \
    CMPX_Q(K, J) }

__device__ __forceinline__ void sort64(float (&s)[QN], float (&e)[QN], int lane) {
    ST_DPP_Q(2, 1, 0xB1)
    ST_DPP_Q(4, 2, 0x4E)  ST_DPP_Q(4, 1, 0xB1)
    ST_SWZ_Q(8, 4, 0x101F) ST_DPP_Q(8, 2, 0x4E) ST_DPP_Q(8, 1, 0xB1)
    ST_DPP_Q(16, 8, 0x128) ST_SWZ_Q(16, 4, 0x101F) ST_DPP_Q(16, 2, 0x4E) ST_DPP_Q(16, 1, 0xB1)
    ST_SWZ_Q(32, 16, 0x401F) ST_DPP_Q(32, 8, 0x128) ST_SWZ_Q(32, 4, 0x101F) ST_DPP_Q(32, 2, 0x4E) ST_DPP_Q(32, 1, 0xB1)
    ST_SHF_Q(64, 32)
    ST_SWZ_Q(64, 16, 0x401F) ST_DPP_Q(64, 8, 0x128) ST_SWZ_Q(64, 4, 0x101F) ST_DPP_Q(64, 2, 0x4E) ST_DPP_Q(64, 1, 0xB1)
}

// ---------- wave64 inclusive scans via DPP, arrays for ILP ----------

__device__ __forceinline__ void scan_max_q(float (&x)[QN]) {
    const float NI = __int_as_float(0xFF800000u);
#define SMSTEP(CTRL, RM) { _Pragma("unroll") for (int q = 0; q < QN; ++q) \
        x[q] = fmaxf(x[q], dppf<CTRL, RM, false>(x[q], NI)); }
    SMSTEP(0x111, 0xF) SMSTEP(0x112, 0xF) SMSTEP(0x114, 0xF)
    SMSTEP(0x118, 0xF) SMSTEP(0x142, 0xA) SMSTEP(0x143, 0xC)
#undef SMSTEP
}

__device__ __forceinline__ void scan_sum2_q(float (&a)[QN], float (&b)[QN]) {
#define SSSTEP(CTRL, RM) { \
    _Pragma("unroll") for (int q = 0; q < QN; ++q) a[q] += dppf<CTRL, RM, false>(a[q], 0.0f); \
    _Pragma("unroll") for (int q = 0; q < QN; ++q) b[q] += dppf<CTRL, RM, false>(b[q], 0.0f); }
    SSSTEP(0x111, 0xF) SSSTEP(0x112, 0xF) SSSTEP(0x114, 0xF)
    SSSTEP(0x118, 0xF) SSSTEP(0x142, 0xA) SSSTEP(0x143, 0xC)
#undef SSSTEP
}

// ---------- main per-frame kernel: 4 frames per wave ----------
// MODE 0: packed rows to scratch + counts; MODE 1: direct write at offsets; MODE 2: counts only.
template<int MODE>
__global__ __launch_bounds__(256) void frag_kernel(const float2* __restrict__ frags,
                                                   const float* __restrict__ offsets,
                                                   int* __restrict__ counts,
                                                   const int* __restrict__ offs,
                                                   float2* __restrict__ rows,
                                                   float* __restrict__ out) {
    int lane = threadIdx.x & 63;
    int f0 = (blockIdx.x * 4 + (threadIdx.x >> 6)) * QN;

    float s[QN], e[QN];
#pragma unroll
    for (int q = 0; q < QN; ++q) {
        float2 v = frags[(size_t)(f0 + q) * NFRAG + lane];
        s[q] = v.x; e[q] = v.y;
    }
    sort64(s, e, lane);

    float run[QN];
#pragma unroll
    for (int q = 0; q < QN; ++q) run[q] = e[q];
    scan_max_q(run);

    u64 gs[QN];
#pragma unroll
    for (int q = 0; q < QN; ++q) {
        float prev = __shfl_up(run[q], 1, 64);
        bool ng = (lane > 0) && (s[q] > prev);
        gs[q] = __ballot(ng) | 1ull;
    }

    if (MODE == 2) {
        if (lane == 0) {
            int4 c;
            c.x = (int)__popcll(gs[0]); c.y = (int)__popcll(gs[1]);
            c.z = (int)__popcll(gs[2]); c.w = (int)__popcll(gs[3]);
            *(int4*)(counts + f0) = c;
        }
        return;
    }

    u64 le_mask = ((1ull << lane) << 1) - 1ull;   // bits <= lane (lane 63 -> ~0)

    // grid cells & rank (identical FP ops to reference)
    int rank[QN]; u64 r1[QN];
    const float coef = (float)(64.0 / 44100.0);
#pragma unroll
    for (int q = 0; q < QN; ++q) {
        float off = offsets[f0 + q];
        int sc = (int)floorf((s[q] - off) * coef); if (sc < 0) sc = 0;
        int ec = (int)floorf((e[q] - off) * coef); if (ec > 63) ec = 63;
        rank[q] = (sc != 0 && ec != 63) ? 1 : 0;
        r1[q] = __ballot(rank[q] == 1);
    }

    // group span per q from the wave-uniform gs mask
    int startL[QN], endL[QN]; u64 span[QN];
#pragma unroll
    for (int q = 0; q < QN; ++q) {
        startL[q] = 63 - __builtin_clzll(gs[q] & le_mask);
        u64 above = gs[q] & ~le_mask;
        endL[q] = above ? (__builtin_ctzll(above) - 1) : 63;
        span[q] = (((1ull << endL[q]) << 1) - 1ull) & ~((1ull << startL[q]) - 1ull);
    }

    bool ismax[QN]; float cnt[QN];
#pragma unroll
    for (int q = 0; q < QN; ++q) {
        int gmax = ((r1[q] & span[q]) != 0ull) ? 1 : 0;
        ismax[q] = (rank[q] == gmax);
        u64 im = __ballot(ismax[q]);
        cnt[q] = (float)__popcll(im & span[q]);   // >= 1 always
    }

    float ps[QN], pe[QN];
#pragma unroll
    for (int q = 0; q < QN; ++q) {
        ps[q] = ismax[q] ? s[q] : 0.0f;
        pe[q] = ismax[q] ? e[q] : 0.0f;
    }
    scan_sum2_q(ps, pe);

#pragma unroll
    for (int q = 0; q < QN; ++q) {
        float bs = __shfl(ps[q], startL[q] - 1, 64);
        float be = __shfl(pe[q], startL[q] - 1, 64);
        if (startL[q] == 0) { bs = 0.0f; be = 0.0f; }
        int gid = (int)__popcll(gs[q] & le_mask) - 1;
        if (lane == endL[q]) {
            float2 r;
            r.x = (ps[q] - bs) / cnt[q];
            r.y = (pe[q] - be) / cnt[q];
            int frame = f0 + q;
            if (MODE == 0) {
                rows[(size_t)frame * NFRAG + gid] = r;
            } else {
                int b = frame >> 9;
                ((float2*)out)[(size_t)b * TROWS + offs[frame] + gid] = r;
            }
        }
    }
    if (MODE == 0 && lane == 0) {
        int4 c;
        c.x = (int)__popcll(gs[0]); c.y = (int)__popcll(gs[1]);
        c.z = (int)__popcll(gs[2]); c.w = (int)__popcll(gs[3]);
        *(int4*)(counts + f0) = c;
    }
}

// ---------- per-batch exclusive scan of frame group counts ----------

__global__ __launch_bounds__(512) void scan_kernel(const int* __restrict__ cnt,
                                                   int* __restrict__ offs,
                                                   int* __restrict__ totals,
                                                   float* __restrict__ out_tail) {
    __shared__ int tmp[NF];
    int b = blockIdx.x, t = threadIdx.x;
    int v = cnt[b * NF + t];
    tmp[t] = v;
    __syncthreads();
    for (int d = 1; d < NF; d <<= 1) {
        int x = (t >= d) ? tmp[t - d] : 0;
        __syncthreads();
        tmp[t] += x;
        __syncthreads();
    }
    offs[b * NF + t] = tmp[t] - v;                   // exclusive
    if (t == NF - 1) {
        totals[b] = tmp[NF - 1];
        out_tail[b] = (float)tmp[NF - 1];
    }
}

// ---------- compaction: scratch rows -> final batch-global rows (4 frames/wave) ----------

__global__ __launch_bounds__(256) void compact_kernel(const float2* __restrict__ rows,
                                                      const int* __restrict__ cnt,
                                                      const int* __restrict__ offs,
                                                      float* __restrict__ out) {
    int lane = threadIdx.x & 63;
    int f0 = (blockIdx.x * 4 + (threadIdx.x >> 6)) * QN;
#pragma unroll
    for (int q = 0; q < QN; ++q) {
        int frame = f0 + q;
        int G = cnt[frame];
        if (lane < G) {
            int b = frame >> 9;
            ((float2*)out)[(size_t)b * TROWS + offs[frame] + lane] =
                rows[(size_t)frame * NFRAG + lane];
        }
    }
}

// ---------- zero only the padding rows, float4 stores ----------

__global__ __launch_bounds__(256) void ztail_kernel(const int* __restrict__ totals,
                                                    float* __restrict__ out) {
    int idx = blockIdx.x * 256 + threadIdx.x;        // one thread = 2 rows
    int b = idx >> 14;                               // / (TROWS/2)
    int r0 = (idx & 16383) * 2;
    int ng = totals[b];
    if (r0 >= ng) {
        *(float4*)(out + ((size_t)b * TROWS + r0) * 2) = make_float4(0.f, 0.f, 0.f, 0.f);
    } else if (r0 + 1 >= ng) {
        *(float2*)(out + ((size_t)b * TROWS + r0 + 1) * 2) = make_float2(0.f, 0.f);
    }
}

extern "C" void kernel_launch(void* const* d_in, const int* in_sizes, int n_in,
                              void* d_out, int out_size, void* d_ws, size_t ws_size,
                              hipStream_t stream) {
    const float2* frags = (const float2*)d_in[0];   // [B,F,N,2] f32
    const float* offsets = (const float*)d_in[1];   // [B,F] f32
    float* out = (float*)d_out;

    int* counts = (int*)d_ws;
    int* offs = counts + NFRAMES;
    int* totals = offs + NFRAMES;
    float2* rows = (float2*)((char*)d_ws + ((size_t)2 * NFRAMES + NB + 2) * sizeof(int));
    size_t small = ((size_t)2 * NFRAMES + NB + 2) * sizeof(int);
    size_t need = small + (size_t)NFRAMES * NFRAG * sizeof(float2);

    float* tail = out + (size_t)NB * TROWS * 2;

    if (ws_size >= need) {
        frag_kernel<0><<<NFRAMES / 16, 256, 0, stream>>>(frags, offsets, counts, nullptr, rows, nullptr);
        scan_kernel<<<NB, NF, 0, stream>>>(counts, offs, totals, tail);
        compact_kernel<<<NFRAMES / 16, 256, 0, stream>>>(rows, counts, offs, out);
        ztail_kernel<<<NB * TROWS / 2 / 256, 256, 0, stream>>>(totals, out);
    } else {
        frag_kernel<2><<<NFRAMES / 16, 256, 0, stream>>>(frags, offsets, counts, nullptr, nullptr, nullptr);
        scan_kernel<<<NB, NF, 0, stream>>>(counts, offs, totals, tail);
        frag_kernel<1><<<NFRAMES / 16, 256, 0, stream>>>(frags, offsets, counts, offs, nullptr, out);
        ztail_kernel<<<NB * TROWS / 2 / 256, 256, 0, stream>>>(totals, out);
    }
}